// Round 2
// baseline (3115.665 us; speedup 1.0000x reference)
//
#include <hip/hip_runtime.h>

#define NN 50000
#define NE 800000

typedef __attribute__((ext_vector_type(4))) float f32x4;
typedef __bf16 bf16x8 __attribute__((ext_vector_type(8)));

__device__ __forceinline__ unsigned short f2bf(float f) {
  unsigned u = __float_as_uint(f);
  u += 0x7fffu + ((u >> 16) & 1u);
  return (unsigned short)(u >> 16);
}

// ---------------- edge MLP: ew = softplus(relu(ea@Wm1+bm1)@Wm2+bm2); deg[row]+=ew
__global__ __launch_bounds__(256) void edge_mlp_kernel(
    const float* __restrict__ ea,
    const float* __restrict__ Wm1, const float* __restrict__ bm1,
    const float* __restrict__ Wm2, const float* __restrict__ bm2,
    const int* __restrict__ ei, float* __restrict__ wE, float* __restrict__ deg) {
  __shared__ float w1[512];
  __shared__ float b1[32];
  __shared__ float w2[32];
  __shared__ float b2s[1];
  const int t = threadIdx.x;
  w1[t] = Wm1[t];
  w1[t + 256] = Wm1[t + 256];
  if (t < 32) { b1[t] = bm1[t]; w2[t] = Wm2[t]; }
  if (t == 0) b2s[0] = bm2[0];
  __syncthreads();
  const int e = blockIdx.x * 256 + t;
  if (e >= NE) return;
  f32x4 r0 = *(const f32x4*)(ea + e * 16);
  f32x4 r1 = *(const f32x4*)(ea + e * 16 + 4);
  f32x4 r2 = *(const f32x4*)(ea + e * 16 + 8);
  f32x4 r3 = *(const f32x4*)(ea + e * 16 + 12);
  float a[16];
#pragma unroll
  for (int i = 0; i < 4; i++) {
    a[i] = r0[i]; a[4 + i] = r1[i]; a[8 + i] = r2[i]; a[12 + i] = r3[i];
  }
  float h[32];
#pragma unroll
  for (int j = 0; j < 32; j++) h[j] = b1[j];
#pragma unroll
  for (int i = 0; i < 16; i++) {
    const float ai = a[i];
    const f32x4* wr = (const f32x4*)&w1[i * 32];
#pragma unroll
    for (int j4 = 0; j4 < 8; j4++) {
      f32x4 wvv = wr[j4];
      h[j4 * 4 + 0] = fmaf(ai, wvv[0], h[j4 * 4 + 0]);
      h[j4 * 4 + 1] = fmaf(ai, wvv[1], h[j4 * 4 + 1]);
      h[j4 * 4 + 2] = fmaf(ai, wvv[2], h[j4 * 4 + 2]);
      h[j4 * 4 + 3] = fmaf(ai, wvv[3], h[j4 * 4 + 3]);
    }
  }
  float s = b2s[0];
#pragma unroll
  for (int j = 0; j < 32; j++) s = fmaf(fmaxf(h[j], 0.0f), w2[j], s);
  const float sp = (s > 0.0f) ? (s + log1pf(expf(-s))) : log1pf(expf(s));
  wE[e] = sp;
  unsafeAtomicAdd(&deg[ei[e]], sp);
}

// ---------------- w[e] = ew[e] / fix(deg[row])
__global__ __launch_bounds__(256) void wnorm_kernel(
    const int* __restrict__ ei, const float* __restrict__ deg, float* __restrict__ wE) {
  const int e = blockIdx.x * 256 + threadIdx.x;
  if (e >= NE) return;
  float d = deg[ei[e]];
  d = (d < 0.5f) ? d + 1.0f : d;
  wE[e] = wE[e] / d;
}

// ---------------- transform GEMM: xm = mix(mask, relu(x@Wt1+bt1), relu(x@Wt0+bt0)) -> bf16
__global__ __launch_bounds__(256) void gemm_transform(
    const float* __restrict__ X,
    const float* __restrict__ W1, const float* __restrict__ W0,
    const float* __restrict__ bias1, const float* __restrict__ bias0,
    const int* __restrict__ mask, unsigned short* __restrict__ xmb) {
  __shared__ __align__(16) unsigned short As[64 * 40];
  __shared__ __align__(16) unsigned short Bs1[64 * 40];
  __shared__ __align__(16) unsigned short Bs0[64 * 40];
  const int t = threadIdx.x;
  const int row0 = blockIdx.x * 64;
  const int col0 = blockIdx.y * 64;
  const int wv = t >> 6, lane = t & 63, m = lane & 15, q = lane >> 4;
  const int ar = t >> 2, cg = t & 3;
  const int bk = t >> 3, ng = t & 7;
  f32x4 acc1[4], acc0[4];
#pragma unroll
  for (int i = 0; i < 4; i++) { acc1[i] = (f32x4)(0.0f); acc0[i] = (f32x4)(0.0f); }
  const int gr = row0 + ar;
  for (int k0 = 0; k0 < 256; k0 += 32) {
    // A tile: 8 fp32 -> 8 bf16 per thread
    unsigned short av[8];
    if (gr < NN) {
      f32x4 x0 = *(const f32x4*)(X + gr * 256 + k0 + cg * 8);
      f32x4 x1 = *(const f32x4*)(X + gr * 256 + k0 + cg * 8 + 4);
#pragma unroll
      for (int i = 0; i < 4; i++) { av[i] = f2bf(x0[i]); av[4 + i] = f2bf(x1[i]); }
    } else {
#pragma unroll
      for (int i = 0; i < 8; i++) av[i] = 0;
    }
    *(uint4*)&As[ar * 40 + cg * 8] = *(const uint4*)av;
    // B tiles (transposed store to LDS)
    f32x4 b1a = *(const f32x4*)(W1 + (k0 + bk) * 256 + col0 + ng * 8);
    f32x4 b1b = *(const f32x4*)(W1 + (k0 + bk) * 256 + col0 + ng * 8 + 4);
    f32x4 b0a = *(const f32x4*)(W0 + (k0 + bk) * 256 + col0 + ng * 8);
    f32x4 b0b = *(const f32x4*)(W0 + (k0 + bk) * 256 + col0 + ng * 8 + 4);
#pragma unroll
    for (int i = 0; i < 4; i++) {
      Bs1[(ng * 8 + i) * 40 + bk] = f2bf(b1a[i]);
      Bs1[(ng * 8 + 4 + i) * 40 + bk] = f2bf(b1b[i]);
      Bs0[(ng * 8 + i) * 40 + bk] = f2bf(b0a[i]);
      Bs0[(ng * 8 + 4 + i) * 40 + bk] = f2bf(b0b[i]);
    }
    __syncthreads();
    bf16x8 af = *(const bf16x8*)&As[(wv * 16 + m) * 40 + q * 8];
#pragma unroll
    for (int nt = 0; nt < 4; nt++) {
      bf16x8 bf1 = *(const bf16x8*)&Bs1[(nt * 16 + m) * 40 + q * 8];
      bf16x8 bf0 = *(const bf16x8*)&Bs0[(nt * 16 + m) * 40 + q * 8];
      acc1[nt] = __builtin_amdgcn_mfma_f32_16x16x32_bf16(af, bf1, acc1[nt], 0, 0, 0);
      acc0[nt] = __builtin_amdgcn_mfma_f32_16x16x32_bf16(af, bf0, acc0[nt], 0, 0, 0);
    }
    __syncthreads();
  }
  const int rbase = row0 + wv * 16 + q * 4;
  int mk[4];
#pragma unroll
  for (int r = 0; r < 4; r++) mk[r] = (rbase + r < NN) ? mask[rbase + r] : 0;
#pragma unroll
  for (int nt = 0; nt < 4; nt++) {
    const int gc = col0 + nt * 16 + m;
    const float bb1 = bias1[gc];
    const float bb0 = bias0[gc];
#pragma unroll
    for (int r = 0; r < 4; r++) {
      const int grr = rbase + r;
      if (grr < NN) {
        float v1 = fmaxf(acc1[nt][r] + bb1, 0.0f);
        float v0 = fmaxf(acc0[nt][r] + bb0, 0.0f);
        float o = mk[r] ? (0.8f * v1 + 0.2f * v0) : (0.8f * v0 + 0.2f * v1);
        xmb[grr * 256 + gc] = f2bf(o);
      }
    }
  }
}

// ---------------- scatter: agg[row] += w[e] * xm[col]  (one wave per edge)
__global__ __launch_bounds__(256) void scatter_kernel(
    const int* __restrict__ ei, const float* __restrict__ wE,
    const unsigned short* __restrict__ xmb, float* __restrict__ agg) {
  const int e = blockIdx.x * 4 + (threadIdx.x >> 6);
  const int lane = threadIdx.x & 63;
  const int row = ei[e];
  const int col = ei[NE + e];
  const float wv = wE[e];
  uint2 u = *(const uint2*)(xmb + col * 256 + lane * 4);
  float v0 = __uint_as_float(u.x << 16);
  float v1 = __uint_as_float(u.x & 0xffff0000u);
  float v2 = __uint_as_float(u.y << 16);
  float v3 = __uint_as_float(u.y & 0xffff0000u);
  float* dst = agg + row * 256 + lane * 4;
  unsafeAtomicAdd(dst + 0, wv * v0);
  unsafeAtomicAdd(dst + 1, wv * v1);
  unsafeAtomicAdd(dst + 2, wv * v2);
  unsafeAtomicAdd(dst + 3, wv * v3);
}

// ---------------- per-channel sums for GraphNorm
__global__ __launch_bounds__(256) void stats_kernel(
    const float* __restrict__ agg, float* __restrict__ S1, float* __restrict__ S2) {
  const int c = threadIdx.x;
  const int r0 = blockIdx.x * 200;
  float s1 = 0.0f, s2 = 0.0f;
  for (int r = 0; r < 200; r++) {
    float v = agg[(r0 + r) * 256 + c];
    s1 += v;
    s2 = fmaf(v, v, s2);
  }
  unsafeAtomicAdd(&S1[c], s1);
  unsafeAtomicAdd(&S2[c], s2);
}

__global__ void finalize_kernel(
    const float* __restrict__ S1, const float* __restrict__ S2,
    const float* __restrict__ gw, const float* __restrict__ gb,
    const float* __restrict__ ga,
    float* __restrict__ scale, float* __restrict__ shift) {
  const int c = threadIdx.x;
  const float inv_n = 1.0f / (float)NN;
  float mean = S1[c] * inv_n;
  float ex2 = S2[c] * inv_n;
  float am = ga[c] * mean;                     // alpha*mean
  float var = ex2 - 2.0f * am * mean + am * am;  // E[(agg - am)^2]
  float sc = gw[c] * rsqrtf(var + 1e-5f);
  scale[c] = sc;
  shift[c] = gb[c] - sc * am;
}

// ---------------- combine GEMM: out = mix(mask, xc@Wc1+bc1, xc@Wc0+bc0), xc=[norm(agg), x]
__global__ __launch_bounds__(256) void gemm_combine(
    const float* __restrict__ agg, const float* __restrict__ scale, const float* __restrict__ shift,
    const float* __restrict__ X,
    const float* __restrict__ W1, const float* __restrict__ W0,
    const float* __restrict__ bias1, const float* __restrict__ bias0,
    const int* __restrict__ mask, float* __restrict__ out) {
  __shared__ __align__(16) unsigned short As[64 * 40];
  __shared__ __align__(16) unsigned short Bs1[64 * 40];
  __shared__ __align__(16) unsigned short Bs0[64 * 40];
  __shared__ float scL[256];
  __shared__ float shL[256];
  const int t = threadIdx.x;
  scL[t] = scale[t];
  shL[t] = shift[t];
  const int row0 = blockIdx.x * 64;
  const int col0 = blockIdx.y * 64;
  const int wv = t >> 6, lane = t & 63, m = lane & 15, q = lane >> 4;
  const int ar = t >> 2, cg = t & 3;
  const int bk = t >> 3, ng = t & 7;
  f32x4 acc1[4], acc0[4];
#pragma unroll
  for (int i = 0; i < 4; i++) { acc1[i] = (f32x4)(0.0f); acc0[i] = (f32x4)(0.0f); }
  const int gr = row0 + ar;
  __syncthreads();  // scL/shL ready
  for (int k0 = 0; k0 < 512; k0 += 32) {
    unsigned short av[8];
#pragma unroll
    for (int i = 0; i < 8; i++) av[i] = 0;
    if (gr < NN) {
      if (k0 < 256) {
        const int c0 = k0 + cg * 8;
        f32x4 v0 = *(const f32x4*)(agg + gr * 256 + c0);
        f32x4 v1 = *(const f32x4*)(agg + gr * 256 + c0 + 4);
#pragma unroll
        for (int i = 0; i < 4; i++) {
          av[i] = f2bf(fmaf(scL[c0 + i], v0[i], shL[c0 + i]));
          av[4 + i] = f2bf(fmaf(scL[c0 + 4 + i], v1[i], shL[c0 + 4 + i]));
        }
      } else {
        f32x4 x0 = *(const f32x4*)(X + gr * 256 + (k0 - 256) + cg * 8);
        f32x4 x1 = *(const f32x4*)(X + gr * 256 + (k0 - 256) + cg * 8 + 4);
#pragma unroll
        for (int i = 0; i < 4; i++) { av[i] = f2bf(x0[i]); av[4 + i] = f2bf(x1[i]); }
      }
    }
    *(uint4*)&As[ar * 40 + cg * 8] = *(const uint4*)av;
    f32x4 b1a = *(const f32x4*)(W1 + (k0 + bk) * 256 + col0 + ng * 8);
    f32x4 b1b = *(const f32x4*)(W1 + (k0 + bk) * 256 + col0 + ng * 8 + 4);
    f32x4 b0a = *(const f32x4*)(W0 + (k0 + bk) * 256 + col0 + ng * 8);
    f32x4 b0b = *(const f32x4*)(W0 + (k0 + bk) * 256 + col0 + ng * 8 + 4);
#pragma unroll
    for (int i = 0; i < 4; i++) {
      Bs1[(ng * 8 + i) * 40 + bk] = f2bf(b1a[i]);
      Bs1[(ng * 8 + 4 + i) * 40 + bk] = f2bf(b1b[i]);
      Bs0[(ng * 8 + i) * 40 + bk] = f2bf(b0a[i]);
      Bs0[(ng * 8 + 4 + i) * 40 + bk] = f2bf(b0b[i]);
    }
    __syncthreads();
    bf16x8 af = *(const bf16x8*)&As[(wv * 16 + m) * 40 + q * 8];
#pragma unroll
    for (int nt = 0; nt < 4; nt++) {
      bf16x8 bf1 = *(const bf16x8*)&Bs1[(nt * 16 + m) * 40 + q * 8];
      bf16x8 bf0 = *(const bf16x8*)&Bs0[(nt * 16 + m) * 40 + q * 8];
      acc1[nt] = __builtin_amdgcn_mfma_f32_16x16x32_bf16(af, bf1, acc1[nt], 0, 0, 0);
      acc0[nt] = __builtin_amdgcn_mfma_f32_16x16x32_bf16(af, bf0, acc0[nt], 0, 0, 0);
    }
    __syncthreads();
  }
  const int rbase = row0 + wv * 16 + q * 4;
  int mk[4];
#pragma unroll
  for (int r = 0; r < 4; r++) mk[r] = (rbase + r < NN) ? mask[rbase + r] : 0;
#pragma unroll
  for (int nt = 0; nt < 4; nt++) {
    const int gc = col0 + nt * 16 + m;
    const float bb1 = bias1[gc];
    const float bb0 = bias0[gc];
#pragma unroll
    for (int r = 0; r < 4; r++) {
      const int grr = rbase + r;
      if (grr < NN) {
        float v1 = acc1[nt][r] + bb1;
        float v0 = acc0[nt][r] + bb0;
        float o = mk[r] ? (0.8f * v1 + 0.2f * v0) : (0.8f * v0 + 0.2f * v1);
        out[grr * 256 + gc] = o;
      }
    }
  }
}

extern "C" void kernel_launch(void* const* d_in, const int* in_sizes, int n_in,
                              void* d_out, int out_size, void* d_ws, size_t ws_size,
                              hipStream_t stream) {
  (void)in_sizes; (void)n_in; (void)out_size; (void)ws_size;
  const float* x   = (const float*)d_in[0];
  const int*   ei  = (const int*)d_in[1];
  // d_in[2] edge_weight: unused by reference (scalar-mode edge MLP replaces it)
  const int*   msk = (const int*)d_in[3];
  const float* ea  = (const float*)d_in[4];
  const float* Wt0 = (const float*)d_in[5];
  const float* bt0 = (const float*)d_in[6];
  const float* Wt1 = (const float*)d_in[7];
  const float* bt1 = (const float*)d_in[8];
  const float* Wc0 = (const float*)d_in[9];
  const float* bc0 = (const float*)d_in[10];
  const float* Wc1 = (const float*)d_in[11];
  const float* bc1 = (const float*)d_in[12];
  const float* gnw = (const float*)d_in[13];
  const float* gnb = (const float*)d_in[14];
  const float* gna = (const float*)d_in[15];
  const float* Wm1 = (const float*)d_in[16];
  const float* bm1 = (const float*)d_in[17];
  const float* Wm2 = (const float*)d_in[18];
  const float* bm2 = (const float*)d_in[19];

  // workspace layout (bytes):
  //   [0, 200192)            deg (NN f32, padded)
  //   [200192, 204288)       stats: S1|S2|scale|shift (256 f32 each)
  //   [204288, 51404288)     agg (NN*256 f32)
  //   [51404288, 77004288)   xm (NN*256 bf16)
  //   [77004288, 80204288)   wE (NE f32)
  char* ws = (char*)d_ws;
  float* deg    = (float*)ws;
  float* S1     = (float*)(ws + 200192);
  float* S2     = (float*)(ws + 200192 + 1024);
  float* scaleP = (float*)(ws + 200192 + 2048);
  float* shiftP = (float*)(ws + 200192 + 3072);
  float* agg    = (float*)(ws + 204288);
  unsigned short* xmb = (unsigned short*)(ws + 51404288);
  float* wE     = (float*)(ws + 77004288);

  hipMemsetAsync(ws, 0, 51404288, stream);  // deg + stats + agg

  edge_mlp_kernel<<<3125, 256, 0, stream>>>(ea, Wm1, bm1, Wm2, bm2, ei, wE, deg);
  wnorm_kernel<<<3125, 256, 0, stream>>>(ei, deg, wE);
  gemm_transform<<<dim3(782, 4), 256, 0, stream>>>(x, Wt1, Wt0, bt1, bt0, msk, xmb);
  scatter_kernel<<<200000, 256, 0, stream>>>(ei, wE, xmb, agg);
  stats_kernel<<<250, 256, 0, stream>>>(agg, S1, S2);
  finalize_kernel<<<1, 256, 0, stream>>>(S1, S2, gnw, gnb, gna, scaleP, shiftP);
  gemm_combine<<<dim3(782, 4), 256, 0, stream>>>(agg, scaleP, shiftP, x, Wc1, Wc0,
                                                 bc1, bc0, msk, (float*)d_out);
}

// Round 3
// 585.234 us; speedup vs baseline: 5.3238x; 5.3238x over previous
//
#include <hip/hip_runtime.h>

#define NN 50000
#define NE 800000
#define NNP 50176  // 196*256

typedef __attribute__((ext_vector_type(4))) float f32x4;
typedef __bf16 bf16x8 __attribute__((ext_vector_type(8)));

__device__ __forceinline__ float bfu2f(unsigned short u) {
  return __uint_as_float(((unsigned)u) << 16);
}
__device__ __forceinline__ unsigned short f2bf(float f) {
  unsigned u = __float_as_uint(f);
  u += 0x7fffu + ((u >> 16) & 1u);
  return (unsigned short)(u >> 16);
}

// ---------------- edge MLP: ew = softplus(...); deg[row]+=ew; cnt[row]++
__global__ __launch_bounds__(256) void edge_mlp_kernel(
    const float* __restrict__ ea,
    const float* __restrict__ Wm1, const float* __restrict__ bm1,
    const float* __restrict__ Wm2, const float* __restrict__ bm2,
    const int* __restrict__ ei, float* __restrict__ wE, float* __restrict__ deg,
    int* __restrict__ cnt) {
  __shared__ float w1[512];
  __shared__ float b1[32];
  __shared__ float w2[32];
  __shared__ float b2s[1];
  const int t = threadIdx.x;
  w1[t] = Wm1[t];
  w1[t + 256] = Wm1[t + 256];
  if (t < 32) { b1[t] = bm1[t]; w2[t] = Wm2[t]; }
  if (t == 0) b2s[0] = bm2[0];
  __syncthreads();
  const int e = blockIdx.x * 256 + t;
  if (e >= NE) return;
  f32x4 r0 = *(const f32x4*)(ea + e * 16);
  f32x4 r1 = *(const f32x4*)(ea + e * 16 + 4);
  f32x4 r2 = *(const f32x4*)(ea + e * 16 + 8);
  f32x4 r3 = *(const f32x4*)(ea + e * 16 + 12);
  float a[16];
#pragma unroll
  for (int i = 0; i < 4; i++) {
    a[i] = r0[i]; a[4 + i] = r1[i]; a[8 + i] = r2[i]; a[12 + i] = r3[i];
  }
  float h[32];
#pragma unroll
  for (int j = 0; j < 32; j++) h[j] = b1[j];
#pragma unroll
  for (int i = 0; i < 16; i++) {
    const float ai = a[i];
    const f32x4* wr = (const f32x4*)&w1[i * 32];
#pragma unroll
    for (int j4 = 0; j4 < 8; j4++) {
      f32x4 wvv = wr[j4];
      h[j4 * 4 + 0] = fmaf(ai, wvv[0], h[j4 * 4 + 0]);
      h[j4 * 4 + 1] = fmaf(ai, wvv[1], h[j4 * 4 + 1]);
      h[j4 * 4 + 2] = fmaf(ai, wvv[2], h[j4 * 4 + 2]);
      h[j4 * 4 + 3] = fmaf(ai, wvv[3], h[j4 * 4 + 3]);
    }
  }
  float s = b2s[0];
#pragma unroll
  for (int j = 0; j < 32; j++) s = fmaf(fmaxf(h[j], 0.0f), w2[j], s);
  const float sp = (s > 0.0f) ? (s + log1pf(expf(-s))) : log1pf(expf(s));
  wE[e] = sp;
  const int row = ei[e];
  unsafeAtomicAdd(&deg[row], sp);
  atomicAdd(&cnt[row], 1);
}

// ---------------- CSR build: hierarchical exclusive scan of cnt
__global__ __launch_bounds__(256) void scan1_kernel(const int* __restrict__ cnt,
                                                    int* __restrict__ blockSum) {
  __shared__ int sd[256];
  const int t = threadIdx.x;
  sd[t] = cnt[blockIdx.x * 256 + t];
  __syncthreads();
  for (int off = 128; off > 0; off >>= 1) {
    if (t < off) sd[t] += sd[t + off];
    __syncthreads();
  }
  if (t == 0) blockSum[blockIdx.x] = sd[0];
}

__global__ __launch_bounds__(256) void scan2_kernel(int* __restrict__ blockSum) {
  __shared__ int sd[256];
  const int t = threadIdx.x;
  int v = (t < 196) ? blockSum[t] : 0;
  sd[t] = v;
  __syncthreads();
  for (int off = 1; off < 256; off <<= 1) {
    int y = (t >= off) ? sd[t - off] : 0;
    __syncthreads();
    sd[t] += y;
    __syncthreads();
  }
  int ex = (t == 0) ? 0 : sd[t - 1];
  __syncthreads();
  if (t < 196) blockSum[t] = ex;
}

__global__ __launch_bounds__(256) void scan3_kernel(
    const int* __restrict__ cnt, const int* __restrict__ blockSum,
    int* __restrict__ start, int* __restrict__ cursor) {
  __shared__ int sd[256];
  const int t = threadIdx.x;
  const int row = blockIdx.x * 256 + t;
  const int c = cnt[row];
  sd[t] = c;
  __syncthreads();
  for (int off = 1; off < 256; off <<= 1) {
    int y = (t >= off) ? sd[t - off] : 0;
    __syncthreads();
    sd[t] += y;
    __syncthreads();
  }
  const int st = blockSum[blockIdx.x] + sd[t] - c;  // exclusive
  start[row] = st;
  cursor[row] = st;
}

// ---------------- normalize + fill CSR buckets
__global__ __launch_bounds__(256) void wnorm_fill_kernel(
    const int* __restrict__ ei, const float* __restrict__ deg,
    const float* __restrict__ wE, int* __restrict__ cursor,
    int* __restrict__ colS, float* __restrict__ wS) {
  const int e = blockIdx.x * 256 + threadIdx.x;
  if (e >= NE) return;
  const int row = ei[e];
  float d = deg[row];
  d = (d < 0.5f) ? d + 1.0f : d;
  const float w = wE[e] / d;
  const int pos = atomicAdd(&cursor[row], 1);
  colS[pos] = ei[NE + e];
  wS[pos] = w;
}

// ---------------- transform GEMM: xm = mix(mask, relu(x@Wt1+bt1), relu(x@Wt0+bt0)) -> bf16
__global__ __launch_bounds__(256) void gemm_transform(
    const float* __restrict__ X,
    const float* __restrict__ W1, const float* __restrict__ W0,
    const float* __restrict__ bias1, const float* __restrict__ bias0,
    const int* __restrict__ mask, unsigned short* __restrict__ xmb) {
  __shared__ __align__(16) unsigned short As[64 * 40];
  __shared__ __align__(16) unsigned short Bs1[64 * 40];
  __shared__ __align__(16) unsigned short Bs0[64 * 40];
  const int t = threadIdx.x;
  const int row0 = blockIdx.x * 64;
  const int col0 = blockIdx.y * 64;
  const int wv = t >> 6, lane = t & 63, m = lane & 15, q = lane >> 4;
  const int ar = t >> 2, cg = t & 3;
  const int bk = t >> 3, ng = t & 7;
  f32x4 acc1[4], acc0[4];
#pragma unroll
  for (int i = 0; i < 4; i++) { acc1[i] = (f32x4)(0.0f); acc0[i] = (f32x4)(0.0f); }
  const int gr = row0 + ar;
  for (int k0 = 0; k0 < 256; k0 += 32) {
    unsigned short av[8];
    if (gr < NN) {
      f32x4 x0 = *(const f32x4*)(X + gr * 256 + k0 + cg * 8);
      f32x4 x1 = *(const f32x4*)(X + gr * 256 + k0 + cg * 8 + 4);
#pragma unroll
      for (int i = 0; i < 4; i++) { av[i] = f2bf(x0[i]); av[4 + i] = f2bf(x1[i]); }
    } else {
#pragma unroll
      for (int i = 0; i < 8; i++) av[i] = 0;
    }
    *(uint4*)&As[ar * 40 + cg * 8] = *(const uint4*)av;
    f32x4 b1a = *(const f32x4*)(W1 + (k0 + bk) * 256 + col0 + ng * 8);
    f32x4 b1b = *(const f32x4*)(W1 + (k0 + bk) * 256 + col0 + ng * 8 + 4);
    f32x4 b0a = *(const f32x4*)(W0 + (k0 + bk) * 256 + col0 + ng * 8);
    f32x4 b0b = *(const f32x4*)(W0 + (k0 + bk) * 256 + col0 + ng * 8 + 4);
#pragma unroll
    for (int i = 0; i < 4; i++) {
      Bs1[(ng * 8 + i) * 40 + bk] = f2bf(b1a[i]);
      Bs1[(ng * 8 + 4 + i) * 40 + bk] = f2bf(b1b[i]);
      Bs0[(ng * 8 + i) * 40 + bk] = f2bf(b0a[i]);
      Bs0[(ng * 8 + 4 + i) * 40 + bk] = f2bf(b0b[i]);
    }
    __syncthreads();
    bf16x8 af = *(const bf16x8*)&As[(wv * 16 + m) * 40 + q * 8];
#pragma unroll
    for (int nt = 0; nt < 4; nt++) {
      bf16x8 bf1 = *(const bf16x8*)&Bs1[(nt * 16 + m) * 40 + q * 8];
      bf16x8 bf0 = *(const bf16x8*)&Bs0[(nt * 16 + m) * 40 + q * 8];
      acc1[nt] = __builtin_amdgcn_mfma_f32_16x16x32_bf16(af, bf1, acc1[nt], 0, 0, 0);
      acc0[nt] = __builtin_amdgcn_mfma_f32_16x16x32_bf16(af, bf0, acc0[nt], 0, 0, 0);
    }
    __syncthreads();
  }
  const int rbase = row0 + wv * 16 + q * 4;
  int mk[4];
#pragma unroll
  for (int r = 0; r < 4; r++) mk[r] = (rbase + r < NN) ? mask[rbase + r] : 0;
#pragma unroll
  for (int nt = 0; nt < 4; nt++) {
    const int gc = col0 + nt * 16 + m;
    const float bb1 = bias1[gc];
    const float bb0 = bias0[gc];
#pragma unroll
    for (int r = 0; r < 4; r++) {
      const int grr = rbase + r;
      if (grr < NN) {
        float v1 = fmaxf(acc1[nt][r] + bb1, 0.0f);
        float v0 = fmaxf(acc0[nt][r] + bb0, 0.0f);
        float o = mk[r] ? (0.8f * v1 + 0.2f * v0) : (0.8f * v0 + 0.2f * v1);
        xmb[grr * 256 + gc] = f2bf(o);
      }
    }
  }
}

// ---------------- pull-mode aggregation: one wave per row, no atomics
__global__ __launch_bounds__(256) void aggregate_kernel(
    const int* __restrict__ start, const int* __restrict__ cnt,
    const int* __restrict__ colS, const float* __restrict__ wS,
    const unsigned short* __restrict__ xmb, unsigned short* __restrict__ aggb) {
  const int wave = threadIdx.x >> 6, lane = threadIdx.x & 63;
  const int row = blockIdx.x * 4 + wave;
  const int s = start[row];
  const int c = cnt[row];
  const int choff = lane * 4;
  f32x4 acc = (f32x4)(0.0f);
  int i = 0;
  for (; i + 2 <= c; i += 2) {
    const int c0 = colS[s + i], c1 = colS[s + i + 1];
    const float w0 = wS[s + i], w1 = wS[s + i + 1];
    uint2 u0 = *(const uint2*)(xmb + c0 * 256 + choff);
    uint2 u1 = *(const uint2*)(xmb + c1 * 256 + choff);
    acc[0] = fmaf(w0, __uint_as_float(u0.x << 16), acc[0]);
    acc[1] = fmaf(w0, __uint_as_float(u0.x & 0xffff0000u), acc[1]);
    acc[2] = fmaf(w0, __uint_as_float(u0.y << 16), acc[2]);
    acc[3] = fmaf(w0, __uint_as_float(u0.y & 0xffff0000u), acc[3]);
    acc[0] = fmaf(w1, __uint_as_float(u1.x << 16), acc[0]);
    acc[1] = fmaf(w1, __uint_as_float(u1.x & 0xffff0000u), acc[1]);
    acc[2] = fmaf(w1, __uint_as_float(u1.y << 16), acc[2]);
    acc[3] = fmaf(w1, __uint_as_float(u1.y & 0xffff0000u), acc[3]);
  }
  if (i < c) {
    const int c0 = colS[s + i];
    const float w0 = wS[s + i];
    uint2 u0 = *(const uint2*)(xmb + c0 * 256 + choff);
    acc[0] = fmaf(w0, __uint_as_float(u0.x << 16), acc[0]);
    acc[1] = fmaf(w0, __uint_as_float(u0.x & 0xffff0000u), acc[1]);
    acc[2] = fmaf(w0, __uint_as_float(u0.y << 16), acc[2]);
    acc[3] = fmaf(w0, __uint_as_float(u0.y & 0xffff0000u), acc[3]);
  }
  unsigned short o[4];
#pragma unroll
  for (int j = 0; j < 4; j++) o[j] = f2bf(acc[j]);
  *(uint2*)(aggb + row * 256 + choff) = *(const uint2*)o;
}

// ---------------- per-channel sums for GraphNorm (reads bf16 agg)
__global__ __launch_bounds__(256) void stats_kernel(
    const unsigned short* __restrict__ aggb, float* __restrict__ S1, float* __restrict__ S2) {
  const int c = threadIdx.x;
  const int r0 = blockIdx.x * 200;
  float s1 = 0.0f, s2 = 0.0f;
  for (int r = 0; r < 200; r++) {
    float v = bfu2f(aggb[(r0 + r) * 256 + c]);
    s1 += v;
    s2 = fmaf(v, v, s2);
  }
  unsafeAtomicAdd(&S1[c], s1);
  unsafeAtomicAdd(&S2[c], s2);
}

__global__ void finalize_kernel(
    const float* __restrict__ S1, const float* __restrict__ S2,
    const float* __restrict__ gw, const float* __restrict__ gb,
    const float* __restrict__ ga,
    float* __restrict__ scale, float* __restrict__ shift) {
  const int c = threadIdx.x;
  const float inv_n = 1.0f / (float)NN;
  float mean = S1[c] * inv_n;
  float ex2 = S2[c] * inv_n;
  float am = ga[c] * mean;
  float var = ex2 - 2.0f * am * mean + am * am;
  float sc = gw[c] * rsqrtf(var + 1e-5f);
  scale[c] = sc;
  shift[c] = gb[c] - sc * am;
}

// ---------------- combine GEMM: out = mix(mask, xc@Wc1+bc1, xc@Wc0+bc0), xc=[norm(agg), x]
__global__ __launch_bounds__(256) void gemm_combine(
    const unsigned short* __restrict__ aggb,
    const float* __restrict__ scale, const float* __restrict__ shift,
    const float* __restrict__ X,
    const float* __restrict__ W1, const float* __restrict__ W0,
    const float* __restrict__ bias1, const float* __restrict__ bias0,
    const int* __restrict__ mask, float* __restrict__ out) {
  __shared__ __align__(16) unsigned short As[64 * 40];
  __shared__ __align__(16) unsigned short Bs1[64 * 40];
  __shared__ __align__(16) unsigned short Bs0[64 * 40];
  __shared__ float scL[256];
  __shared__ float shL[256];
  const int t = threadIdx.x;
  scL[t] = scale[t];
  shL[t] = shift[t];
  const int row0 = blockIdx.x * 64;
  const int col0 = blockIdx.y * 64;
  const int wv = t >> 6, lane = t & 63, m = lane & 15, q = lane >> 4;
  const int ar = t >> 2, cg = t & 3;
  const int bk = t >> 3, ng = t & 7;
  f32x4 acc1[4], acc0[4];
#pragma unroll
  for (int i = 0; i < 4; i++) { acc1[i] = (f32x4)(0.0f); acc0[i] = (f32x4)(0.0f); }
  const int gr = row0 + ar;
  __syncthreads();  // scL/shL ready
  for (int k0 = 0; k0 < 512; k0 += 32) {
    unsigned short av[8];
#pragma unroll
    for (int i = 0; i < 8; i++) av[i] = 0;
    if (gr < NN) {
      if (k0 < 256) {
        const int c0 = k0 + cg * 8;
        uint4 u = *(const uint4*)(aggb + gr * 256 + c0);
        const unsigned short* us = (const unsigned short*)&u;
#pragma unroll
        for (int i = 0; i < 8; i++) {
          av[i] = f2bf(fmaf(scL[c0 + i], bfu2f(us[i]), shL[c0 + i]));
        }
      } else {
        f32x4 x0 = *(const f32x4*)(X + gr * 256 + (k0 - 256) + cg * 8);
        f32x4 x1 = *(const f32x4*)(X + gr * 256 + (k0 - 256) + cg * 8 + 4);
#pragma unroll
        for (int i = 0; i < 4; i++) { av[i] = f2bf(x0[i]); av[4 + i] = f2bf(x1[i]); }
      }
    }
    *(uint4*)&As[ar * 40 + cg * 8] = *(const uint4*)av;
    f32x4 b1a = *(const f32x4*)(W1 + (k0 + bk) * 256 + col0 + ng * 8);
    f32x4 b1b = *(const f32x4*)(W1 + (k0 + bk) * 256 + col0 + ng * 8 + 4);
    f32x4 b0a = *(const f32x4*)(W0 + (k0 + bk) * 256 + col0 + ng * 8);
    f32x4 b0b = *(const f32x4*)(W0 + (k0 + bk) * 256 + col0 + ng * 8 + 4);
#pragma unroll
    for (int i = 0; i < 4; i++) {
      Bs1[(ng * 8 + i) * 40 + bk] = f2bf(b1a[i]);
      Bs1[(ng * 8 + 4 + i) * 40 + bk] = f2bf(b1b[i]);
      Bs0[(ng * 8 + i) * 40 + bk] = f2bf(b0a[i]);
      Bs0[(ng * 8 + 4 + i) * 40 + bk] = f2bf(b0b[i]);
    }
    __syncthreads();
    bf16x8 af = *(const bf16x8*)&As[(wv * 16 + m) * 40 + q * 8];
#pragma unroll
    for (int nt = 0; nt < 4; nt++) {
      bf16x8 bf1 = *(const bf16x8*)&Bs1[(nt * 16 + m) * 40 + q * 8];
      bf16x8 bf0 = *(const bf16x8*)&Bs0[(nt * 16 + m) * 40 + q * 8];
      acc1[nt] = __builtin_amdgcn_mfma_f32_16x16x32_bf16(af, bf1, acc1[nt], 0, 0, 0);
      acc0[nt] = __builtin_amdgcn_mfma_f32_16x16x32_bf16(af, bf0, acc0[nt], 0, 0, 0);
    }
    __syncthreads();
  }
  const int rbase = row0 + wv * 16 + q * 4;
  int mk[4];
#pragma unroll
  for (int r = 0; r < 4; r++) mk[r] = (rbase + r < NN) ? mask[rbase + r] : 0;
#pragma unroll
  for (int nt = 0; nt < 4; nt++) {
    const int gc = col0 + nt * 16 + m;
    const float bb1 = bias1[gc];
    const float bb0 = bias0[gc];
#pragma unroll
    for (int r = 0; r < 4; r++) {
      const int grr = rbase + r;
      if (grr < NN) {
        float v1 = acc1[nt][r] + bb1;
        float v0 = acc0[nt][r] + bb0;
        float o = mk[r] ? (0.8f * v1 + 0.2f * v0) : (0.8f * v0 + 0.2f * v1);
        out[grr * 256 + gc] = o;
      }
    }
  }
}

extern "C" void kernel_launch(void* const* d_in, const int* in_sizes, int n_in,
                              void* d_out, int out_size, void* d_ws, size_t ws_size,
                              hipStream_t stream) {
  (void)in_sizes; (void)n_in; (void)out_size; (void)ws_size;
  const float* x   = (const float*)d_in[0];
  const int*   ei  = (const int*)d_in[1];
  const int*   msk = (const int*)d_in[3];
  const float* ea  = (const float*)d_in[4];
  const float* Wt0 = (const float*)d_in[5];
  const float* bt0 = (const float*)d_in[6];
  const float* Wt1 = (const float*)d_in[7];
  const float* bt1 = (const float*)d_in[8];
  const float* Wc0 = (const float*)d_in[9];
  const float* bc0 = (const float*)d_in[10];
  const float* Wc1 = (const float*)d_in[11];
  const float* bc1 = (const float*)d_in[12];
  const float* gnw = (const float*)d_in[13];
  const float* gnb = (const float*)d_in[14];
  const float* gna = (const float*)d_in[15];
  const float* Wm1 = (const float*)d_in[16];
  const float* bm1 = (const float*)d_in[17];
  const float* Wm2 = (const float*)d_in[18];
  const float* bm2 = (const float*)d_in[19];

  // workspace layout (bytes), total 58.65 MB:
  //   [0, 200704)              deg f32[NNP]
  //   [200704, 401408)         cnt i32[NNP]
  //   [401408, 602112)         start i32[NNP]
  //   [602112, 802816)         cursor i32[NNP]
  //   [802816, 803840)         blockSum i32[256]
  //   [803840, 807936)         S1|S2|scale|shift f32[256] each
  //   [1048576, 4248576)       colS i32[NE]
  //   [4248576, 7448576)       wS f32[NE]
  //   [7448576, 33048576)      xm bf16[NN*256]
  //   [33048576, 58648576)     agg bf16[NN*256]   (wE f32[NE] aliased at base,
  //                                               dead before agg is written)
  char* ws = (char*)d_ws;
  float* deg    = (float*)ws;
  int* cnt      = (int*)(ws + 200704);
  int* startA   = (int*)(ws + 401408);
  int* cursor   = (int*)(ws + 602112);
  int* blockSum = (int*)(ws + 802816);
  float* S1     = (float*)(ws + 803840);
  float* S2     = (float*)(ws + 803840 + 1024);
  float* scaleP = (float*)(ws + 803840 + 2048);
  float* shiftP = (float*)(ws + 803840 + 3072);
  int* colS     = (int*)(ws + 1048576);
  float* wS     = (float*)(ws + 4248576);
  unsigned short* xmb  = (unsigned short*)(ws + 7448576);
  unsigned short* aggb = (unsigned short*)(ws + 33048576);
  float* wE     = (float*)(ws + 33048576);  // alias, dead before aggregate

  hipMemsetAsync(ws, 0, 1048576, stream);  // deg, cnt, cursor, stats

  edge_mlp_kernel<<<3125, 256, 0, stream>>>(ea, Wm1, bm1, Wm2, bm2, ei, wE, deg, cnt);
  scan1_kernel<<<196, 256, 0, stream>>>(cnt, blockSum);
  scan2_kernel<<<1, 256, 0, stream>>>(blockSum);
  scan3_kernel<<<196, 256, 0, stream>>>(cnt, blockSum, startA, cursor);
  gemm_transform<<<dim3(782, 4), 256, 0, stream>>>(x, Wt1, Wt0, bt1, bt0, msk, xmb);
  wnorm_fill_kernel<<<3125, 256, 0, stream>>>(ei, deg, wE, cursor, colS, wS);
  aggregate_kernel<<<12500, 256, 0, stream>>>(startA, cnt, colS, wS, xmb, aggb);
  stats_kernel<<<250, 256, 0, stream>>>(aggb, S1, S2);
  finalize_kernel<<<1, 256, 0, stream>>>(S1, S2, gnw, gnb, gna, scaleP, shiftP);
  gemm_combine<<<dim3(782, 4), 256, 0, stream>>>(aggb, scaleP, shiftP, x, Wc1, Wc0,
                                                 bc1, bc0, msk, (float*)d_out);
}

// Round 4
// 516.045 us; speedup vs baseline: 6.0376x; 1.1341x over previous
//
#include <hip/hip_runtime.h>

#define NN 50000
#define NE 800000
#define NNP 50176  // 196*256

typedef __attribute__((ext_vector_type(4))) float f32x4;
typedef __bf16 bf16x8 __attribute__((ext_vector_type(8)));

__device__ __forceinline__ float bfu2f(unsigned short u) {
  return __uint_as_float(((unsigned)u) << 16);
}
__device__ __forceinline__ unsigned short f2bf(float f) {
  unsigned u = __float_as_uint(f);
  u += 0x7fffu + ((u >> 16) & 1u);
  return (unsigned short)(u >> 16);
}

// ---------------- weight prep: W[K][N] fp32 -> WT[N][K] bf16 (run once per launch)
__global__ __launch_bounds__(256) void transpose_w(
    const float* __restrict__ W, unsigned short* __restrict__ WT, int K, int N) {
  __shared__ unsigned short T[32 * 40];
  const int t = threadIdx.x;
  const int k0 = blockIdx.x * 32, n0 = blockIdx.y * 32;
  const int kk = t >> 3, nn = (t & 7) * 4;
  f32x4 v = *(const f32x4*)(W + (k0 + kk) * N + n0 + nn);
#pragma unroll
  for (int i = 0; i < 4; i++) T[(nn + i) * 40 + kk] = f2bf(v[i]);
  __syncthreads();
  const int nn2 = t >> 3, kk2 = (t & 7) * 4;
  unsigned short o[4];
#pragma unroll
  for (int i = 0; i < 4; i++) o[i] = T[nn2 * 40 + kk2 + i];
  *(uint2*)(WT + (n0 + nn2) * K + k0 + kk2) = *(const uint2*)o;
}

// ---------------- edge MLP: ew = softplus(...); deg[row]+=ew; cnt[row]++
__global__ __launch_bounds__(256) void edge_mlp_kernel(
    const float* __restrict__ ea,
    const float* __restrict__ Wm1, const float* __restrict__ bm1,
    const float* __restrict__ Wm2, const float* __restrict__ bm2,
    const int* __restrict__ ei, float* __restrict__ wE, float* __restrict__ deg,
    int* __restrict__ cnt) {
  __shared__ float w1[512];
  __shared__ float b1[32];
  __shared__ float w2[32];
  __shared__ float b2s[1];
  const int t = threadIdx.x;
  w1[t] = Wm1[t];
  w1[t + 256] = Wm1[t + 256];
  if (t < 32) { b1[t] = bm1[t]; w2[t] = Wm2[t]; }
  if (t == 0) b2s[0] = bm2[0];
  __syncthreads();
  const int e = blockIdx.x * 256 + t;
  if (e >= NE) return;
  f32x4 r0 = *(const f32x4*)(ea + e * 16);
  f32x4 r1 = *(const f32x4*)(ea + e * 16 + 4);
  f32x4 r2 = *(const f32x4*)(ea + e * 16 + 8);
  f32x4 r3 = *(const f32x4*)(ea + e * 16 + 12);
  float a[16];
#pragma unroll
  for (int i = 0; i < 4; i++) {
    a[i] = r0[i]; a[4 + i] = r1[i]; a[8 + i] = r2[i]; a[12 + i] = r3[i];
  }
  float h[32];
#pragma unroll
  for (int j = 0; j < 32; j++) h[j] = b1[j];
#pragma unroll
  for (int i = 0; i < 16; i++) {
    const float ai = a[i];
    const f32x4* wr = (const f32x4*)&w1[i * 32];
#pragma unroll
    for (int j4 = 0; j4 < 8; j4++) {
      f32x4 wvv = wr[j4];
      h[j4 * 4 + 0] = fmaf(ai, wvv[0], h[j4 * 4 + 0]);
      h[j4 * 4 + 1] = fmaf(ai, wvv[1], h[j4 * 4 + 1]);
      h[j4 * 4 + 2] = fmaf(ai, wvv[2], h[j4 * 4 + 2]);
      h[j4 * 4 + 3] = fmaf(ai, wvv[3], h[j4 * 4 + 3]);
    }
  }
  float s = b2s[0];
#pragma unroll
  for (int j = 0; j < 32; j++) s = fmaf(fmaxf(h[j], 0.0f), w2[j], s);
  const float sp = (s > 0.0f) ? (s + log1pf(expf(-s))) : log1pf(expf(s));
  wE[e] = sp;
  const int row = ei[e];
  unsafeAtomicAdd(&deg[row], sp);
  atomicAdd(&cnt[row], 1);
}

// ---------------- CSR build: hierarchical exclusive scan of cnt
__global__ __launch_bounds__(256) void scan1_kernel(const int* __restrict__ cnt,
                                                    int* __restrict__ blockSum) {
  __shared__ int sd[256];
  const int t = threadIdx.x;
  sd[t] = cnt[blockIdx.x * 256 + t];
  __syncthreads();
  for (int off = 128; off > 0; off >>= 1) {
    if (t < off) sd[t] += sd[t + off];
    __syncthreads();
  }
  if (t == 0) blockSum[blockIdx.x] = sd[0];
}

__global__ __launch_bounds__(256) void scan2_kernel(int* __restrict__ blockSum) {
  __shared__ int sd[256];
  const int t = threadIdx.x;
  int v = (t < 196) ? blockSum[t] : 0;
  sd[t] = v;
  __syncthreads();
  for (int off = 1; off < 256; off <<= 1) {
    int y = (t >= off) ? sd[t - off] : 0;
    __syncthreads();
    sd[t] += y;
    __syncthreads();
  }
  int ex = (t == 0) ? 0 : sd[t - 1];
  __syncthreads();
  if (t < 196) blockSum[t] = ex;
}

__global__ __launch_bounds__(256) void scan3_kernel(
    const int* __restrict__ cnt, const int* __restrict__ blockSum,
    int* __restrict__ start, int* __restrict__ cursor) {
  __shared__ int sd[256];
  const int t = threadIdx.x;
  const int row = blockIdx.x * 256 + t;
  const int c = cnt[row];
  sd[t] = c;
  __syncthreads();
  for (int off = 1; off < 256; off <<= 1) {
    int y = (t >= off) ? sd[t - off] : 0;
    __syncthreads();
    sd[t] += y;
    __syncthreads();
  }
  const int st = blockSum[blockIdx.x] + sd[t] - c;  // exclusive
  start[row] = st;
  cursor[row] = st;
}

// ---------------- normalize + fill CSR buckets
__global__ __launch_bounds__(256) void wnorm_fill_kernel(
    const int* __restrict__ ei, const float* __restrict__ deg,
    const float* __restrict__ wE, int* __restrict__ cursor,
    int* __restrict__ colS, float* __restrict__ wS) {
  const int e = blockIdx.x * 256 + threadIdx.x;
  if (e >= NE) return;
  const int row = ei[e];
  float d = deg[row];
  d = (d < 0.5f) ? d + 1.0f : d;
  const float w = wE[e] / d;
  const int pos = atomicAdd(&cursor[row], 1);
  colS[pos] = ei[NE + e];
  wS[pos] = w;
}

// ---------------- transform GEMM (128x128 tile): xm = mix(mask, relu(x@Wt1+bt1), relu(x@Wt0+bt0))
__global__ __launch_bounds__(256, 2) void gemm_transform(
    const float* __restrict__ X,
    const unsigned short* __restrict__ WT1, const unsigned short* __restrict__ WT0,
    const float* __restrict__ bias1, const float* __restrict__ bias0,
    const int* __restrict__ mask, unsigned short* __restrict__ xmb) {
  __shared__ __align__(16) unsigned short As[128 * 40];
  __shared__ __align__(16) unsigned short Bs1[128 * 40];
  __shared__ __align__(16) unsigned short Bs0[128 * 40];
  const int t = threadIdx.x;
  const int col0 = blockIdx.x * 128, row0 = blockIdx.y * 128;
  const int wv = t >> 6, lane = t & 63, m = lane & 15, q = lane >> 4;
  const int hr = t >> 1, hc = t & 1;  // staging: row/n index 0..127, k-half 0/1
  f32x4 acc1[2][8], acc0[2][8];
#pragma unroll
  for (int rf = 0; rf < 2; rf++)
#pragma unroll
    for (int nt = 0; nt < 8; nt++) { acc1[rf][nt] = (f32x4)(0.0f); acc0[rf][nt] = (f32x4)(0.0f); }
  const int gr = row0 + hr;
  for (int k0 = 0; k0 < 256; k0 += 32) {
    unsigned short av[16];
    if (gr < NN) {
      const float* xp = X + gr * 256 + k0 + hc * 16;
      f32x4 x0 = *(const f32x4*)(xp);
      f32x4 x1 = *(const f32x4*)(xp + 4);
      f32x4 x2 = *(const f32x4*)(xp + 8);
      f32x4 x3 = *(const f32x4*)(xp + 12);
#pragma unroll
      for (int i = 0; i < 4; i++) {
        av[i] = f2bf(x0[i]); av[4 + i] = f2bf(x1[i]);
        av[8 + i] = f2bf(x2[i]); av[12 + i] = f2bf(x3[i]);
      }
    } else {
#pragma unroll
      for (int i = 0; i < 16; i++) av[i] = 0;
    }
    *(uint4*)&As[hr * 40 + hc * 16] = ((const uint4*)av)[0];
    *(uint4*)&As[hr * 40 + hc * 16 + 8] = ((const uint4*)av)[1];
    const unsigned short* w1p = WT1 + (col0 + hr) * 256 + k0 + hc * 16;
    const unsigned short* w0p = WT0 + (col0 + hr) * 256 + k0 + hc * 16;
    uint4 b1a = *(const uint4*)w1p;
    uint4 b1b = *(const uint4*)(w1p + 8);
    uint4 b0a = *(const uint4*)w0p;
    uint4 b0b = *(const uint4*)(w0p + 8);
    *(uint4*)&Bs1[hr * 40 + hc * 16] = b1a;
    *(uint4*)&Bs1[hr * 40 + hc * 16 + 8] = b1b;
    *(uint4*)&Bs0[hr * 40 + hc * 16] = b0a;
    *(uint4*)&Bs0[hr * 40 + hc * 16 + 8] = b0b;
    __syncthreads();
    bf16x8 af[2];
#pragma unroll
    for (int rf = 0; rf < 2; rf++)
      af[rf] = *(const bf16x8*)&As[(wv * 32 + rf * 16 + m) * 40 + q * 8];
#pragma unroll
    for (int nt = 0; nt < 8; nt++) {
      bf16x8 f1 = *(const bf16x8*)&Bs1[(nt * 16 + m) * 40 + q * 8];
      bf16x8 f0 = *(const bf16x8*)&Bs0[(nt * 16 + m) * 40 + q * 8];
      acc1[0][nt] = __builtin_amdgcn_mfma_f32_16x16x32_bf16(af[0], f1, acc1[0][nt], 0, 0, 0);
      acc1[1][nt] = __builtin_amdgcn_mfma_f32_16x16x32_bf16(af[1], f1, acc1[1][nt], 0, 0, 0);
      acc0[0][nt] = __builtin_amdgcn_mfma_f32_16x16x32_bf16(af[0], f0, acc0[0][nt], 0, 0, 0);
      acc0[1][nt] = __builtin_amdgcn_mfma_f32_16x16x32_bf16(af[1], f0, acc0[1][nt], 0, 0, 0);
    }
    __syncthreads();
  }
#pragma unroll
  for (int rf = 0; rf < 2; rf++) {
    const int rbase = row0 + wv * 32 + rf * 16 + q * 4;
    int mk[4];
#pragma unroll
    for (int r = 0; r < 4; r++) mk[r] = (rbase + r < NN) ? mask[rbase + r] : 0;
#pragma unroll
    for (int nt = 0; nt < 8; nt++) {
      const int gc = col0 + nt * 16 + m;
      const float bb1 = bias1[gc];
      const float bb0 = bias0[gc];
#pragma unroll
      for (int r = 0; r < 4; r++) {
        const int grr = rbase + r;
        if (grr < NN) {
          float v1 = fmaxf(acc1[rf][nt][r] + bb1, 0.0f);
          float v0 = fmaxf(acc0[rf][nt][r] + bb0, 0.0f);
          float o = mk[r] ? (0.8f * v1 + 0.2f * v0) : (0.8f * v0 + 0.2f * v1);
          xmb[grr * 256 + gc] = f2bf(o);
        }
      }
    }
  }
}

// ---------------- pull-mode aggregation: one wave per row, no atomics
__global__ __launch_bounds__(256) void aggregate_kernel(
    const int* __restrict__ start, const int* __restrict__ cnt,
    const int* __restrict__ colS, const float* __restrict__ wS,
    const unsigned short* __restrict__ xmb, unsigned short* __restrict__ aggb) {
  const int wave = threadIdx.x >> 6, lane = threadIdx.x & 63;
  const int row = blockIdx.x * 4 + wave;
  const int s = start[row];
  const int c = cnt[row];
  const int choff = lane * 4;
  f32x4 acc = (f32x4)(0.0f);
  int i = 0;
  for (; i + 2 <= c; i += 2) {
    const int c0 = colS[s + i], c1 = colS[s + i + 1];
    const float w0 = wS[s + i], w1 = wS[s + i + 1];
    uint2 u0 = *(const uint2*)(xmb + c0 * 256 + choff);
    uint2 u1 = *(const uint2*)(xmb + c1 * 256 + choff);
    acc[0] = fmaf(w0, __uint_as_float(u0.x << 16), acc[0]);
    acc[1] = fmaf(w0, __uint_as_float(u0.x & 0xffff0000u), acc[1]);
    acc[2] = fmaf(w0, __uint_as_float(u0.y << 16), acc[2]);
    acc[3] = fmaf(w0, __uint_as_float(u0.y & 0xffff0000u), acc[3]);
    acc[0] = fmaf(w1, __uint_as_float(u1.x << 16), acc[0]);
    acc[1] = fmaf(w1, __uint_as_float(u1.x & 0xffff0000u), acc[1]);
    acc[2] = fmaf(w1, __uint_as_float(u1.y << 16), acc[2]);
    acc[3] = fmaf(w1, __uint_as_float(u1.y & 0xffff0000u), acc[3]);
  }
  if (i < c) {
    const int c0 = colS[s + i];
    const float w0 = wS[s + i];
    uint2 u0 = *(const uint2*)(xmb + c0 * 256 + choff);
    acc[0] = fmaf(w0, __uint_as_float(u0.x << 16), acc[0]);
    acc[1] = fmaf(w0, __uint_as_float(u0.x & 0xffff0000u), acc[1]);
    acc[2] = fmaf(w0, __uint_as_float(u0.y << 16), acc[2]);
    acc[3] = fmaf(w0, __uint_as_float(u0.y & 0xffff0000u), acc[3]);
  }
  unsigned short o[4];
#pragma unroll
  for (int j = 0; j < 4; j++) o[j] = f2bf(acc[j]);
  *(uint2*)(aggb + row * 256 + choff) = *(const uint2*)o;
}

// ---------------- per-channel sums for GraphNorm (reads bf16 agg)
__global__ __launch_bounds__(256) void stats_kernel(
    const unsigned short* __restrict__ aggb, float* __restrict__ S1, float* __restrict__ S2) {
  const int c = threadIdx.x;
  const int r0 = blockIdx.x * 200;
  float s1 = 0.0f, s2 = 0.0f;
  for (int r = 0; r < 200; r++) {
    float v = bfu2f(aggb[(r0 + r) * 256 + c]);
    s1 += v;
    s2 = fmaf(v, v, s2);
  }
  unsafeAtomicAdd(&S1[c], s1);
  unsafeAtomicAdd(&S2[c], s2);
}

__global__ void finalize_kernel(
    const float* __restrict__ S1, const float* __restrict__ S2,
    const float* __restrict__ gw, const float* __restrict__ gb,
    const float* __restrict__ ga,
    float* __restrict__ scale, float* __restrict__ shift) {
  const int c = threadIdx.x;
  const float inv_n = 1.0f / (float)NN;
  float mean = S1[c] * inv_n;
  float ex2 = S2[c] * inv_n;
  float am = ga[c] * mean;
  float var = ex2 - 2.0f * am * mean + am * am;
  float sc = gw[c] * rsqrtf(var + 1e-5f);
  scale[c] = sc;
  shift[c] = gb[c] - sc * am;
}

// ---------------- combine GEMM (128x128 tile): out = mix(mask, xc@Wc1+bc1, xc@Wc0+bc0)
__global__ __launch_bounds__(256, 2) void gemm_combine(
    const unsigned short* __restrict__ aggb,
    const float* __restrict__ scale, const float* __restrict__ shift,
    const float* __restrict__ X,
    const unsigned short* __restrict__ WT1, const unsigned short* __restrict__ WT0,
    const float* __restrict__ bias1, const float* __restrict__ bias0,
    const int* __restrict__ mask, float* __restrict__ out) {
  __shared__ __align__(16) unsigned short As[128 * 40];
  __shared__ __align__(16) unsigned short Bs1[128 * 40];
  __shared__ __align__(16) unsigned short Bs0[128 * 40];
  __shared__ float scL[256];
  __shared__ float shL[256];
  const int t = threadIdx.x;
  scL[t] = scale[t];
  shL[t] = shift[t];
  const int col0 = blockIdx.x * 128, row0 = blockIdx.y * 128;
  const int wv = t >> 6, lane = t & 63, m = lane & 15, q = lane >> 4;
  const int hr = t >> 1, hc = t & 1;
  f32x4 acc1[2][8], acc0[2][8];
#pragma unroll
  for (int rf = 0; rf < 2; rf++)
#pragma unroll
    for (int nt = 0; nt < 8; nt++) { acc1[rf][nt] = (f32x4)(0.0f); acc0[rf][nt] = (f32x4)(0.0f); }
  const int gr = row0 + hr;
  __syncthreads();  // scL/shL ready
  for (int k0 = 0; k0 < 512; k0 += 32) {
    unsigned short av[16];
#pragma unroll
    for (int i = 0; i < 16; i++) av[i] = 0;
    if (gr < NN) {
      if (k0 < 256) {
        const int c0 = k0 + hc * 16;
        uint4 ua = *(const uint4*)(aggb + gr * 256 + c0);
        uint4 ub = *(const uint4*)(aggb + gr * 256 + c0 + 8);
        const unsigned short* us = (const unsigned short*)&ua;
        const unsigned short* vs = (const unsigned short*)&ub;
#pragma unroll
        for (int i = 0; i < 8; i++) {
          av[i] = f2bf(fmaf(scL[c0 + i], bfu2f(us[i]), shL[c0 + i]));
          av[8 + i] = f2bf(fmaf(scL[c0 + 8 + i], bfu2f(vs[i]), shL[c0 + 8 + i]));
        }
      } else {
        const float* xp = X + gr * 256 + (k0 - 256) + hc * 16;
        f32x4 x0 = *(const f32x4*)(xp);
        f32x4 x1 = *(const f32x4*)(xp + 4);
        f32x4 x2 = *(const f32x4*)(xp + 8);
        f32x4 x3 = *(const f32x4*)(xp + 12);
#pragma unroll
        for (int i = 0; i < 4; i++) {
          av[i] = f2bf(x0[i]); av[4 + i] = f2bf(x1[i]);
          av[8 + i] = f2bf(x2[i]); av[12 + i] = f2bf(x3[i]);
        }
      }
    }
    *(uint4*)&As[hr * 40 + hc * 16] = ((const uint4*)av)[0];
    *(uint4*)&As[hr * 40 + hc * 16 + 8] = ((const uint4*)av)[1];
    const unsigned short* w1p = WT1 + (col0 + hr) * 512 + k0 + hc * 16;
    const unsigned short* w0p = WT0 + (col0 + hr) * 512 + k0 + hc * 16;
    uint4 b1a = *(const uint4*)w1p;
    uint4 b1b = *(const uint4*)(w1p + 8);
    uint4 b0a = *(const uint4*)w0p;
    uint4 b0b = *(const uint4*)(w0p + 8);
    *(uint4*)&Bs1[hr * 40 + hc * 16] = b1a;
    *(uint4*)&Bs1[hr * 40 + hc * 16 + 8] = b1b;
    *(uint4*)&Bs0[hr * 40 + hc * 16] = b0a;
    *(uint4*)&Bs0[hr * 40 + hc * 16 + 8] = b0b;
    __syncthreads();
    bf16x8 af[2];
#pragma unroll
    for (int rf = 0; rf < 2; rf++)
      af[rf] = *(const bf16x8*)&As[(wv * 32 + rf * 16 + m) * 40 + q * 8];
#pragma unroll
    for (int nt = 0; nt < 8; nt++) {
      bf16x8 f1 = *(const bf16x8*)&Bs1[(nt * 16 + m) * 40 + q * 8];
      bf16x8 f0 = *(const bf16x8*)&Bs0[(nt * 16 + m) * 40 + q * 8];
      acc1[0][nt] = __builtin_amdgcn_mfma_f32_16x16x32_bf16(af[0], f1, acc1[0][nt], 0, 0, 0);
      acc1[1][nt] = __builtin_amdgcn_mfma_f32_16x16x32_bf16(af[1], f1, acc1[1][nt], 0, 0, 0);
      acc0[0][nt] = __builtin_amdgcn_mfma_f32_16x16x32_bf16(af[0], f0, acc0[0][nt], 0, 0, 0);
      acc0[1][nt] = __builtin_amdgcn_mfma_f32_16x16x32_bf16(af[1], f0, acc0[1][nt], 0, 0, 0);
    }
    __syncthreads();
  }
#pragma unroll
  for (int rf = 0; rf < 2; rf++) {
    const int rbase = row0 + wv * 32 + rf * 16 + q * 4;
    int mk[4];
#pragma unroll
    for (int r = 0; r < 4; r++) mk[r] = (rbase + r < NN) ? mask[rbase + r] : 0;
#pragma unroll
    for (int nt = 0; nt < 8; nt++) {
      const int gc = col0 + nt * 16 + m;
      const float bb1 = bias1[gc];
      const float bb0 = bias0[gc];
#pragma unroll
      for (int r = 0; r < 4; r++) {
        const int grr = rbase + r;
        if (grr < NN) {
          float v1 = acc1[rf][nt][r] + bb1;
          float v0 = acc0[rf][nt][r] + bb0;
          float o = mk[r] ? (0.8f * v1 + 0.2f * v0) : (0.8f * v0 + 0.2f * v1);
          out[grr * 256 + gc] = o;
        }
      }
    }
  }
}

extern "C" void kernel_launch(void* const* d_in, const int* in_sizes, int n_in,
                              void* d_out, int out_size, void* d_ws, size_t ws_size,
                              hipStream_t stream) {
  (void)in_sizes; (void)n_in; (void)out_size; (void)ws_size;
  const float* x   = (const float*)d_in[0];
  const int*   ei  = (const int*)d_in[1];
  const int*   msk = (const int*)d_in[3];
  const float* ea  = (const float*)d_in[4];
  const float* Wt0 = (const float*)d_in[5];
  const float* bt0 = (const float*)d_in[6];
  const float* Wt1 = (const float*)d_in[7];
  const float* bt1 = (const float*)d_in[8];
  const float* Wc0 = (const float*)d_in[9];
  const float* bc0 = (const float*)d_in[10];
  const float* Wc1 = (const float*)d_in[11];
  const float* bc1 = (const float*)d_in[12];
  const float* gnw = (const float*)d_in[13];
  const float* gnb = (const float*)d_in[14];
  const float* gna = (const float*)d_in[15];
  const float* Wm1 = (const float*)d_in[16];
  const float* bm1 = (const float*)d_in[17];
  const float* Wm2 = (const float*)d_in[18];
  const float* bm2 = (const float*)d_in[19];

  // workspace layout (bytes):
  //   [0, 200704)              deg f32[NNP]
  //   [200704, 401408)         cnt i32[NNP]
  //   [401408, 602112)         start i32[NNP]
  //   [602112, 802816)         cursor i32[NNP]
  //   [802816, 803840)         blockSum i32[256]
  //   [803840, 807936)         S1|S2|scale|shift f32[256] each
  //   [1048576, 4248576)       colS i32[NE]
  //   [4248576, 7448576)       wS f32[NE]
  //   [7448576, 33048576)      xm bf16[NN*256]
  //   [33048576, 58648576)     agg bf16[NN*256]   (wE f32[NE] aliased, dead before agg)
  //   [58648576, 58779648)     WTt1 bf16[256*256]
  //   [58779648, 58910720)     WTt0 bf16[256*256]
  //   [58910720, 59172864)     WTc1 bf16[256*512]
  //   [59172864, 59435008)     WTc0 bf16[256*512]
  char* ws = (char*)d_ws;
  float* deg    = (float*)ws;
  int* cnt      = (int*)(ws + 200704);
  int* startA   = (int*)(ws + 401408);
  int* cursor   = (int*)(ws + 602112);
  int* blockSum = (int*)(ws + 802816);
  float* S1     = (float*)(ws + 803840);
  float* S2     = (float*)(ws + 803840 + 1024);
  float* scaleP = (float*)(ws + 803840 + 2048);
  float* shiftP = (float*)(ws + 803840 + 3072);
  int* colS     = (int*)(ws + 1048576);
  float* wS     = (float*)(ws + 4248576);
  unsigned short* xmb  = (unsigned short*)(ws + 7448576);
  unsigned short* aggb = (unsigned short*)(ws + 33048576);
  float* wE     = (float*)(ws + 33048576);  // alias, dead before aggregate
  unsigned short* WTt1 = (unsigned short*)(ws + 58648576);
  unsigned short* WTt0 = (unsigned short*)(ws + 58779648);
  unsigned short* WTc1 = (unsigned short*)(ws + 58910720);
  unsigned short* WTc0 = (unsigned short*)(ws + 59172864);

  hipMemsetAsync(ws, 0, 1048576, stream);  // deg, cnt, cursor, stats

  transpose_w<<<dim3(8, 8), 256, 0, stream>>>(Wt1, WTt1, 256, 256);
  transpose_w<<<dim3(8, 8), 256, 0, stream>>>(Wt0, WTt0, 256, 256);
  transpose_w<<<dim3(16, 8), 256, 0, stream>>>(Wc1, WTc1, 512, 256);
  transpose_w<<<dim3(16, 8), 256, 0, stream>>>(Wc0, WTc0, 512, 256);

  edge_mlp_kernel<<<3125, 256, 0, stream>>>(ea, Wm1, bm1, Wm2, bm2, ei, wE, deg, cnt);
  scan1_kernel<<<196, 256, 0, stream>>>(cnt, blockSum);
  scan2_kernel<<<1, 256, 0, stream>>>(blockSum);
  scan3_kernel<<<196, 256, 0, stream>>>(cnt, blockSum, startA, cursor);
  gemm_transform<<<dim3(2, 391), 256, 0, stream>>>(x, WTt1, WTt0, bt1, bt0, msk, xmb);
  wnorm_fill_kernel<<<3125, 256, 0, stream>>>(ei, deg, wE, cursor, colS, wS);
  aggregate_kernel<<<12500, 256, 0, stream>>>(startA, cnt, colS, wS, xmb, aggb);
  stats_kernel<<<250, 256, 0, stream>>>(aggb, S1, S2);
  finalize_kernel<<<1, 256, 0, stream>>>(S1, S2, gnw, gnb, gna, scaleP, shiftP);
  gemm_combine<<<dim3(2, 391), 256, 0, stream>>>(aggb, scaleP, shiftP, x, WTc1, WTc0,
                                                 bc1, bc0, msk, (float*)d_out);
}

// Round 5
// 503.980 us; speedup vs baseline: 6.1821x; 1.0239x over previous
//
#include <hip/hip_runtime.h>

#define NN 50000
#define NE 800000
#define NNP 50176  // 196*256

typedef __attribute__((ext_vector_type(4))) float f32x4;
typedef __bf16 bf16x8 __attribute__((ext_vector_type(8)));

__device__ __forceinline__ float bfu2f(unsigned short u) {
  return __uint_as_float(((unsigned)u) << 16);
}
__device__ __forceinline__ unsigned short f2bf(float f) {
  unsigned u = __float_as_uint(f);
  u += 0x7fffu + ((u >> 16) & 1u);
  return (unsigned short)(u >> 16);
}

// ---------------- weight prep: W[K][N] fp32 -> WT[N][K] bf16 (run once per launch)
__global__ __launch_bounds__(256) void transpose_w(
    const float* __restrict__ W, unsigned short* __restrict__ WT, int K, int N) {
  __shared__ unsigned short T[32 * 40];
  const int t = threadIdx.x;
  const int k0 = blockIdx.x * 32, n0 = blockIdx.y * 32;
  const int kk = t >> 3, nn = (t & 7) * 4;
  f32x4 v = *(const f32x4*)(W + (k0 + kk) * N + n0 + nn);
#pragma unroll
  for (int i = 0; i < 4; i++) T[(nn + i) * 40 + kk] = f2bf(v[i]);
  __syncthreads();
  const int nn2 = t >> 3, kk2 = (t & 7) * 4;
  unsigned short o[4];
#pragma unroll
  for (int i = 0; i < 4; i++) o[i] = T[nn2 * 40 + kk2 + i];
  *(uint2*)(WT + (n0 + nn2) * K + k0 + kk2) = *(const uint2*)o;
}

// ---------------- edge MLP: ew = softplus(...); deg[row]+=ew; cnt[row]++
// All state in explicit vector registers — no indexable arrays (spill-proof).
__device__ __forceinline__ void mlp4(float a0, float a1, float a2, float a3,
                                     const f32x4* __restrict__ w,  // LDS, 4 rows x 8 vec
                                     f32x4& h0, f32x4& h1, f32x4& h2, f32x4& h3,
                                     f32x4& h4, f32x4& h5, f32x4& h6, f32x4& h7) {
  h0 += w[0] * a0;  h1 += w[1] * a0;  h2 += w[2] * a0;  h3 += w[3] * a0;
  h4 += w[4] * a0;  h5 += w[5] * a0;  h6 += w[6] * a0;  h7 += w[7] * a0;
  h0 += w[8] * a1;  h1 += w[9] * a1;  h2 += w[10] * a1; h3 += w[11] * a1;
  h4 += w[12] * a1; h5 += w[13] * a1; h6 += w[14] * a1; h7 += w[15] * a1;
  h0 += w[16] * a2; h1 += w[17] * a2; h2 += w[18] * a2; h3 += w[19] * a2;
  h4 += w[20] * a2; h5 += w[21] * a2; h6 += w[22] * a2; h7 += w[23] * a2;
  h0 += w[24] * a3; h1 += w[25] * a3; h2 += w[26] * a3; h3 += w[27] * a3;
  h4 += w[28] * a3; h5 += w[29] * a3; h6 += w[30] * a3; h7 += w[31] * a3;
}

__device__ __forceinline__ float rdot(f32x4 h, f32x4 w) {
  float s = fmaxf(h[0], 0.0f) * w[0];
  s = fmaf(fmaxf(h[1], 0.0f), w[1], s);
  s = fmaf(fmaxf(h[2], 0.0f), w[2], s);
  s = fmaf(fmaxf(h[3], 0.0f), w[3], s);
  return s;
}

__global__ __launch_bounds__(256) void edge_mlp_kernel(
    const float* __restrict__ ea,
    const float* __restrict__ Wm1, const float* __restrict__ bm1,
    const float* __restrict__ Wm2, const float* __restrict__ bm2,
    const int* __restrict__ ei, float* __restrict__ wE, float* __restrict__ deg,
    int* __restrict__ cnt) {
  __shared__ __align__(16) float w1[512];
  __shared__ __align__(16) float b1[32];
  __shared__ __align__(16) float w2[32];
  __shared__ float b2s[1];
  const int t = threadIdx.x;
  w1[t] = Wm1[t];
  w1[t + 256] = Wm1[t + 256];
  if (t < 32) { b1[t] = bm1[t]; w2[t] = Wm2[t]; }
  if (t == 0) b2s[0] = bm2[0];
  __syncthreads();
  const int e = blockIdx.x * 256 + t;
  if (e >= NE) return;
  f32x4 r0 = *(const f32x4*)(ea + e * 16);
  f32x4 r1 = *(const f32x4*)(ea + e * 16 + 4);
  f32x4 r2 = *(const f32x4*)(ea + e * 16 + 8);
  f32x4 r3 = *(const f32x4*)(ea + e * 16 + 12);
  const f32x4* bv = (const f32x4*)b1;
  f32x4 h0 = bv[0], h1 = bv[1], h2 = bv[2], h3 = bv[3];
  f32x4 h4 = bv[4], h5 = bv[5], h6 = bv[6], h7 = bv[7];
  const f32x4* wv = (const f32x4*)w1;
  mlp4(r0[0], r0[1], r0[2], r0[3], wv, h0, h1, h2, h3, h4, h5, h6, h7);
  mlp4(r1[0], r1[1], r1[2], r1[3], wv + 32, h0, h1, h2, h3, h4, h5, h6, h7);
  mlp4(r2[0], r2[1], r2[2], r2[3], wv + 64, h0, h1, h2, h3, h4, h5, h6, h7);
  mlp4(r3[0], r3[1], r3[2], r3[3], wv + 96, h0, h1, h2, h3, h4, h5, h6, h7);
  const f32x4* w2v = (const f32x4*)w2;
  float s = b2s[0];
  s += rdot(h0, w2v[0]) + rdot(h1, w2v[1]) + rdot(h2, w2v[2]) + rdot(h3, w2v[3]);
  s += rdot(h4, w2v[4]) + rdot(h5, w2v[5]) + rdot(h6, w2v[6]) + rdot(h7, w2v[7]);
  const float sp = (s > 0.0f) ? (s + log1pf(expf(-s))) : log1pf(expf(s));
  wE[e] = sp;
  const int row = ei[e];
  unsafeAtomicAdd(&deg[row], sp);
  atomicAdd(&cnt[row], 1);
}

// ---------------- CSR build: hierarchical exclusive scan of cnt
__global__ __launch_bounds__(256) void scan1_kernel(const int* __restrict__ cnt,
                                                    int* __restrict__ blockSum) {
  __shared__ int sd[256];
  const int t = threadIdx.x;
  sd[t] = cnt[blockIdx.x * 256 + t];
  __syncthreads();
  for (int off = 128; off > 0; off >>= 1) {
    if (t < off) sd[t] += sd[t + off];
    __syncthreads();
  }
  if (t == 0) blockSum[blockIdx.x] = sd[0];
}

__global__ __launch_bounds__(256) void scan2_kernel(int* __restrict__ blockSum) {
  __shared__ int sd[256];
  const int t = threadIdx.x;
  int v = (t < 196) ? blockSum[t] : 0;
  sd[t] = v;
  __syncthreads();
  for (int off = 1; off < 256; off <<= 1) {
    int y = (t >= off) ? sd[t - off] : 0;
    __syncthreads();
    sd[t] += y;
    __syncthreads();
  }
  int ex = (t == 0) ? 0 : sd[t - 1];
  __syncthreads();
  if (t < 196) blockSum[t] = ex;
}

__global__ __launch_bounds__(256) void scan3_kernel(
    const int* __restrict__ cnt, const int* __restrict__ blockSum,
    int* __restrict__ start, int* __restrict__ cursor) {
  __shared__ int sd[256];
  const int t = threadIdx.x;
  const int row = blockIdx.x * 256 + t;
  const int c = cnt[row];
  sd[t] = c;
  __syncthreads();
  for (int off = 1; off < 256; off <<= 1) {
    int y = (t >= off) ? sd[t - off] : 0;
    __syncthreads();
    sd[t] += y;
    __syncthreads();
  }
  const int st = blockSum[blockIdx.x] + sd[t] - c;  // exclusive
  start[row] = st;
  cursor[row] = st;
}

// ---------------- normalize + fill CSR buckets
__global__ __launch_bounds__(256) void wnorm_fill_kernel(
    const int* __restrict__ ei, const float* __restrict__ deg,
    const float* __restrict__ wE, int* __restrict__ cursor,
    int* __restrict__ colS, float* __restrict__ wS) {
  const int e = blockIdx.x * 256 + threadIdx.x;
  if (e >= NE) return;
  const int row = ei[e];
  float d = deg[row];
  d = (d < 0.5f) ? d + 1.0f : d;
  const float w = wE[e] / d;
  const int pos = atomicAdd(&cursor[row], 1);
  colS[pos] = ei[NE + e];
  wS[pos] = w;
}

// ---------------- transform GEMM (128x128 tile): xm = mix(mask, relu(x@Wt1+bt1), relu(x@Wt0+bt0))
__global__ __launch_bounds__(256, 2) void gemm_transform(
    const float* __restrict__ X,
    const unsigned short* __restrict__ WT1, const unsigned short* __restrict__ WT0,
    const float* __restrict__ bias1, const float* __restrict__ bias0,
    const int* __restrict__ mask, unsigned short* __restrict__ xmb) {
  __shared__ __align__(16) unsigned short As[128 * 40];
  __shared__ __align__(16) unsigned short Bs1[128 * 40];
  __shared__ __align__(16) unsigned short Bs0[128 * 40];
  const int t = threadIdx.x;
  const int col0 = blockIdx.x * 128, row0 = blockIdx.y * 128;
  const int wv = t >> 6, lane = t & 63, m = lane & 15, q = lane >> 4;
  const int hr = t >> 1, hc = t & 1;  // staging: row/n index 0..127, k-half 0/1
  f32x4 acc1[2][8], acc0[2][8];
#pragma unroll
  for (int rf = 0; rf < 2; rf++)
#pragma unroll
    for (int nt = 0; nt < 8; nt++) { acc1[rf][nt] = (f32x4)(0.0f); acc0[rf][nt] = (f32x4)(0.0f); }
  const int gr = row0 + hr;
  for (int k0 = 0; k0 < 256; k0 += 32) {
    unsigned short av[16];
    if (gr < NN) {
      const float* xp = X + gr * 256 + k0 + hc * 16;
      f32x4 x0 = *(const f32x4*)(xp);
      f32x4 x1 = *(const f32x4*)(xp + 4);
      f32x4 x2 = *(const f32x4*)(xp + 8);
      f32x4 x3 = *(const f32x4*)(xp + 12);
#pragma unroll
      for (int i = 0; i < 4; i++) {
        av[i] = f2bf(x0[i]); av[4 + i] = f2bf(x1[i]);
        av[8 + i] = f2bf(x2[i]); av[12 + i] = f2bf(x3[i]);
      }
    } else {
#pragma unroll
      for (int i = 0; i < 16; i++) av[i] = 0;
    }
    *(uint4*)&As[hr * 40 + hc * 16] = ((const uint4*)av)[0];
    *(uint4*)&As[hr * 40 + hc * 16 + 8] = ((const uint4*)av)[1];
    const unsigned short* w1p = WT1 + (col0 + hr) * 256 + k0 + hc * 16;
    const unsigned short* w0p = WT0 + (col0 + hr) * 256 + k0 + hc * 16;
    uint4 b1a = *(const uint4*)w1p;
    uint4 b1b = *(const uint4*)(w1p + 8);
    uint4 b0a = *(const uint4*)w0p;
    uint4 b0b = *(const uint4*)(w0p + 8);
    *(uint4*)&Bs1[hr * 40 + hc * 16] = b1a;
    *(uint4*)&Bs1[hr * 40 + hc * 16 + 8] = b1b;
    *(uint4*)&Bs0[hr * 40 + hc * 16] = b0a;
    *(uint4*)&Bs0[hr * 40 + hc * 16 + 8] = b0b;
    __syncthreads();
    bf16x8 af[2];
#pragma unroll
    for (int rf = 0; rf < 2; rf++)
      af[rf] = *(const bf16x8*)&As[(wv * 32 + rf * 16 + m) * 40 + q * 8];
#pragma unroll
    for (int nt = 0; nt < 8; nt++) {
      bf16x8 f1 = *(const bf16x8*)&Bs1[(nt * 16 + m) * 40 + q * 8];
      bf16x8 f0 = *(const bf16x8*)&Bs0[(nt * 16 + m) * 40 + q * 8];
      acc1[0][nt] = __builtin_amdgcn_mfma_f32_16x16x32_bf16(af[0], f1, acc1[0][nt], 0, 0, 0);
      acc1[1][nt] = __builtin_amdgcn_mfma_f32_16x16x32_bf16(af[1], f1, acc1[1][nt], 0, 0, 0);
      acc0[0][nt] = __builtin_amdgcn_mfma_f32_16x16x32_bf16(af[0], f0, acc0[0][nt], 0, 0, 0);
      acc0[1][nt] = __builtin_amdgcn_mfma_f32_16x16x32_bf16(af[1], f0, acc0[1][nt], 0, 0, 0);
    }
    __syncthreads();
  }
#pragma unroll
  for (int rf = 0; rf < 2; rf++) {
    const int rbase = row0 + wv * 32 + rf * 16 + q * 4;
    int mk[4];
#pragma unroll
    for (int r = 0; r < 4; r++) mk[r] = (rbase + r < NN) ? mask[rbase + r] : 0;
#pragma unroll
    for (int nt = 0; nt < 8; nt++) {
      const int gc = col0 + nt * 16 + m;
      const float bb1 = bias1[gc];
      const float bb0 = bias0[gc];
#pragma unroll
      for (int r = 0; r < 4; r++) {
        const int grr = rbase + r;
        if (grr < NN) {
          float v1 = fmaxf(acc1[rf][nt][r] + bb1, 0.0f);
          float v0 = fmaxf(acc0[rf][nt][r] + bb0, 0.0f);
          float o = mk[r] ? (0.8f * v1 + 0.2f * v0) : (0.8f * v0 + 0.2f * v1);
          xmb[grr * 256 + gc] = f2bf(o);
        }
      }
    }
  }
}

// ---------------- pull-mode aggregation: one wave per row, no atomics, 4-deep ILP
__global__ __launch_bounds__(256) void aggregate_kernel(
    const int* __restrict__ start, const int* __restrict__ cnt,
    const int* __restrict__ colS, const float* __restrict__ wS,
    const unsigned short* __restrict__ xmb, unsigned short* __restrict__ aggb) {
  const int wave = threadIdx.x >> 6, lane = threadIdx.x & 63;
  const int row = blockIdx.x * 4 + wave;
  const int s = start[row];
  const int c = cnt[row];
  const int choff = lane * 4;
  f32x4 acc = (f32x4)(0.0f);
  int i = 0;
  for (; i + 4 <= c; i += 4) {
    const int c0 = colS[s + i], c1 = colS[s + i + 1];
    const int c2 = colS[s + i + 2], c3 = colS[s + i + 3];
    const float w0 = wS[s + i], w1 = wS[s + i + 1];
    const float w2 = wS[s + i + 2], w3 = wS[s + i + 3];
    uint2 u0 = *(const uint2*)(xmb + c0 * 256 + choff);
    uint2 u1 = *(const uint2*)(xmb + c1 * 256 + choff);
    uint2 u2 = *(const uint2*)(xmb + c2 * 256 + choff);
    uint2 u3 = *(const uint2*)(xmb + c3 * 256 + choff);
    acc[0] = fmaf(w0, __uint_as_float(u0.x << 16), acc[0]);
    acc[1] = fmaf(w0, __uint_as_float(u0.x & 0xffff0000u), acc[1]);
    acc[2] = fmaf(w0, __uint_as_float(u0.y << 16), acc[2]);
    acc[3] = fmaf(w0, __uint_as_float(u0.y & 0xffff0000u), acc[3]);
    acc[0] = fmaf(w1, __uint_as_float(u1.x << 16), acc[0]);
    acc[1] = fmaf(w1, __uint_as_float(u1.x & 0xffff0000u), acc[1]);
    acc[2] = fmaf(w1, __uint_as_float(u1.y << 16), acc[2]);
    acc[3] = fmaf(w1, __uint_as_float(u1.y & 0xffff0000u), acc[3]);
    acc[0] = fmaf(w2, __uint_as_float(u2.x << 16), acc[0]);
    acc[1] = fmaf(w2, __uint_as_float(u2.x & 0xffff0000u), acc[1]);
    acc[2] = fmaf(w2, __uint_as_float(u2.y << 16), acc[2]);
    acc[3] = fmaf(w2, __uint_as_float(u2.y & 0xffff0000u), acc[3]);
    acc[0] = fmaf(w3, __uint_as_float(u3.x << 16), acc[0]);
    acc[1] = fmaf(w3, __uint_as_float(u3.x & 0xffff0000u), acc[1]);
    acc[2] = fmaf(w3, __uint_as_float(u3.y << 16), acc[2]);
    acc[3] = fmaf(w3, __uint_as_float(u3.y & 0xffff0000u), acc[3]);
  }
  for (; i < c; i++) {
    const int c0 = colS[s + i];
    const float w0 = wS[s + i];
    uint2 u0 = *(const uint2*)(xmb + c0 * 256 + choff);
    acc[0] = fmaf(w0, __uint_as_float(u0.x << 16), acc[0]);
    acc[1] = fmaf(w0, __uint_as_float(u0.x & 0xffff0000u), acc[1]);
    acc[2] = fmaf(w0, __uint_as_float(u0.y << 16), acc[2]);
    acc[3] = fmaf(w0, __uint_as_float(u0.y & 0xffff0000u), acc[3]);
  }
  unsigned short o[4];
#pragma unroll
  for (int j = 0; j < 4; j++) o[j] = f2bf(acc[j]);
  *(uint2*)(aggb + row * 256 + choff) = *(const uint2*)o;
}

// ---------------- per-channel sums for GraphNorm (reads bf16 agg)
__global__ __launch_bounds__(256) void stats_kernel(
    const unsigned short* __restrict__ aggb, float* __restrict__ S1, float* __restrict__ S2) {
  const int c = threadIdx.x;
  const int r0 = blockIdx.x * 200;
  float s1 = 0.0f, s2 = 0.0f;
  for (int r = 0; r < 200; r++) {
    float v = bfu2f(aggb[(r0 + r) * 256 + c]);
    s1 += v;
    s2 = fmaf(v, v, s2);
  }
  unsafeAtomicAdd(&S1[c], s1);
  unsafeAtomicAdd(&S2[c], s2);
}

__global__ void finalize_kernel(
    const float* __restrict__ S1, const float* __restrict__ S2,
    const float* __restrict__ gw, const float* __restrict__ gb,
    const float* __restrict__ ga,
    float* __restrict__ scale, float* __restrict__ shift) {
  const int c = threadIdx.x;
  const float inv_n = 1.0f / (float)NN;
  float mean = S1[c] * inv_n;
  float ex2 = S2[c] * inv_n;
  float am = ga[c] * mean;
  float var = ex2 - 2.0f * am * mean + am * am;
  float sc = gw[c] * rsqrtf(var + 1e-5f);
  scale[c] = sc;
  shift[c] = gb[c] - sc * am;
}

// ---------------- combine GEMM (128x128 tile): out = mix(mask, xc@Wc1+bc1, xc@Wc0+bc0)
__global__ __launch_bounds__(256, 2) void gemm_combine(
    const unsigned short* __restrict__ aggb,
    const float* __restrict__ scale, const float* __restrict__ shift,
    const float* __restrict__ X,
    const unsigned short* __restrict__ WT1, const unsigned short* __restrict__ WT0,
    const float* __restrict__ bias1, const float* __restrict__ bias0,
    const int* __restrict__ mask, float* __restrict__ out) {
  __shared__ __align__(16) unsigned short As[128 * 40];
  __shared__ __align__(16) unsigned short Bs1[128 * 40];
  __shared__ __align__(16) unsigned short Bs0[128 * 40];
  __shared__ float scL[256];
  __shared__ float shL[256];
  const int t = threadIdx.x;
  scL[t] = scale[t];
  shL[t] = shift[t];
  const int col0 = blockIdx.x * 128, row0 = blockIdx.y * 128;
  const int wv = t >> 6, lane = t & 63, m = lane & 15, q = lane >> 4;
  const int hr = t >> 1, hc = t & 1;
  f32x4 acc1[2][8], acc0[2][8];
#pragma unroll
  for (int rf = 0; rf < 2; rf++)
#pragma unroll
    for (int nt = 0; nt < 8; nt++) { acc1[rf][nt] = (f32x4)(0.0f); acc0[rf][nt] = (f32x4)(0.0f); }
  const int gr = row0 + hr;
  __syncthreads();  // scL/shL ready
  for (int k0 = 0; k0 < 512; k0 += 32) {
    unsigned short av[16];
#pragma unroll
    for (int i = 0; i < 16; i++) av[i] = 0;
    if (gr < NN) {
      if (k0 < 256) {
        const int c0 = k0 + hc * 16;
        uint4 ua = *(const uint4*)(aggb + gr * 256 + c0);
        uint4 ub = *(const uint4*)(aggb + gr * 256 + c0 + 8);
        const unsigned short* us = (const unsigned short*)&ua;
        const unsigned short* vs = (const unsigned short*)&ub;
#pragma unroll
        for (int i = 0; i < 8; i++) {
          av[i] = f2bf(fmaf(scL[c0 + i], bfu2f(us[i]), shL[c0 + i]));
          av[8 + i] = f2bf(fmaf(scL[c0 + 8 + i], bfu2f(vs[i]), shL[c0 + 8 + i]));
        }
      } else {
        const float* xp = X + gr * 256 + (k0 - 256) + hc * 16;
        f32x4 x0 = *(const f32x4*)(xp);
        f32x4 x1 = *(const f32x4*)(xp + 4);
        f32x4 x2 = *(const f32x4*)(xp + 8);
        f32x4 x3 = *(const f32x4*)(xp + 12);
#pragma unroll
        for (int i = 0; i < 4; i++) {
          av[i] = f2bf(x0[i]); av[4 + i] = f2bf(x1[i]);
          av[8 + i] = f2bf(x2[i]); av[12 + i] = f2bf(x3[i]);
        }
      }
    }
    *(uint4*)&As[hr * 40 + hc * 16] = ((const uint4*)av)[0];
    *(uint4*)&As[hr * 40 + hc * 16 + 8] = ((const uint4*)av)[1];
    const unsigned short* w1p = WT1 + (col0 + hr) * 512 + k0 + hc * 16;
    const unsigned short* w0p = WT0 + (col0 + hr) * 512 + k0 + hc * 16;
    uint4 b1a = *(const uint4*)w1p;
    uint4 b1b = *(const uint4*)(w1p + 8);
    uint4 b0a = *(const uint4*)w0p;
    uint4 b0b = *(const uint4*)(w0p + 8);
    *(uint4*)&Bs1[hr * 40 + hc * 16] = b1a;
    *(uint4*)&Bs1[hr * 40 + hc * 16 + 8] = b1b;
    *(uint4*)&Bs0[hr * 40 + hc * 16] = b0a;
    *(uint4*)&Bs0[hr * 40 + hc * 16 + 8] = b0b;
    __syncthreads();
    bf16x8 af[2];
#pragma unroll
    for (int rf = 0; rf < 2; rf++)
      af[rf] = *(const bf16x8*)&As[(wv * 32 + rf * 16 + m) * 40 + q * 8];
#pragma unroll
    for (int nt = 0; nt < 8; nt++) {
      bf16x8 f1 = *(const bf16x8*)&Bs1[(nt * 16 + m) * 40 + q * 8];
      bf16x8 f0 = *(const bf16x8*)&Bs0[(nt * 16 + m) * 40 + q * 8];
      acc1[0][nt] = __builtin_amdgcn_mfma_f32_16x16x32_bf16(af[0], f1, acc1[0][nt], 0, 0, 0);
      acc1[1][nt] = __builtin_amdgcn_mfma_f32_16x16x32_bf16(af[1], f1, acc1[1][nt], 0, 0, 0);
      acc0[0][nt] = __builtin_amdgcn_mfma_f32_16x16x32_bf16(af[0], f0, acc0[0][nt], 0, 0, 0);
      acc0[1][nt] = __builtin_amdgcn_mfma_f32_16x16x32_bf16(af[1], f0, acc0[1][nt], 0, 0, 0);
    }
    __syncthreads();
  }
#pragma unroll
  for (int rf = 0; rf < 2; rf++) {
    const int rbase = row0 + wv * 32 + rf * 16 + q * 4;
    int mk[4];
#pragma unroll
    for (int r = 0; r < 4; r++) mk[r] = (rbase + r < NN) ? mask[rbase + r] : 0;
#pragma unroll
    for (int nt = 0; nt < 8; nt++) {
      const int gc = col0 + nt * 16 + m;
      const float bb1 = bias1[gc];
      const float bb0 = bias0[gc];
#pragma unroll
      for (int r = 0; r < 4; r++) {
        const int grr = rbase + r;
        if (grr < NN) {
          float v1 = acc1[rf][nt][r] + bb1;
          float v0 = acc0[rf][nt][r] + bb0;
          float o = mk[r] ? (0.8f * v1 + 0.2f * v0) : (0.8f * v0 + 0.2f * v1);
          out[grr * 256 + gc] = o;
        }
      }
    }
  }
}

extern "C" void kernel_launch(void* const* d_in, const int* in_sizes, int n_in,
                              void* d_out, int out_size, void* d_ws, size_t ws_size,
                              hipStream_t stream) {
  (void)in_sizes; (void)n_in; (void)out_size; (void)ws_size;
  const float* x   = (const float*)d_in[0];
  const int*   ei  = (const int*)d_in[1];
  const int*   msk = (const int*)d_in[3];
  const float* ea  = (const float*)d_in[4];
  const float* Wt0 = (const float*)d_in[5];
  const float* bt0 = (const float*)d_in[6];
  const float* Wt1 = (const float*)d_in[7];
  const float* bt1 = (const float*)d_in[8];
  const float* Wc0 = (const float*)d_in[9];
  const float* bc0 = (const float*)d_in[10];
  const float* Wc1 = (const float*)d_in[11];
  const float* bc1 = (const float*)d_in[12];
  const float* gnw = (const float*)d_in[13];
  const float* gnb = (const float*)d_in[14];
  const float* gna = (const float*)d_in[15];
  const float* Wm1 = (const float*)d_in[16];
  const float* bm1 = (const float*)d_in[17];
  const float* Wm2 = (const float*)d_in[18];
  const float* bm2 = (const float*)d_in[19];

  // workspace layout (bytes):
  //   [0, 200704)              deg f32[NNP]
  //   [200704, 401408)         cnt i32[NNP]
  //   [401408, 602112)         start i32[NNP]
  //   [602112, 802816)         cursor i32[NNP]
  //   [802816, 803840)         blockSum i32[256]
  //   [803840, 807936)         S1|S2|scale|shift f32[256] each
  //   [1048576, 4248576)       colS i32[NE]
  //   [4248576, 7448576)       wS f32[NE]
  //   [7448576, 33048576)      xm bf16[NN*256]
  //   [33048576, 58648576)     agg bf16[NN*256]   (wE f32[NE] aliased, dead before agg)
  //   [58648576, 58779648)     WTt1 bf16[256*256]
  //   [58779648, 58910720)     WTt0 bf16[256*256]
  //   [58910720, 59172864)     WTc1 bf16[256*512]
  //   [59172864, 59435008)     WTc0 bf16[256*512]
  char* ws = (char*)d_ws;
  float* deg    = (float*)ws;
  int* cnt      = (int*)(ws + 200704);
  int* startA   = (int*)(ws + 401408);
  int* cursor   = (int*)(ws + 602112);
  int* blockSum = (int*)(ws + 802816);
  float* S1     = (float*)(ws + 803840);
  float* S2     = (float*)(ws + 803840 + 1024);
  float* scaleP = (float*)(ws + 803840 + 2048);
  float* shiftP = (float*)(ws + 803840 + 3072);
  int* colS     = (int*)(ws + 1048576);
  float* wS     = (float*)(ws + 4248576);
  unsigned short* xmb  = (unsigned short*)(ws + 7448576);
  unsigned short* aggb = (unsigned short*)(ws + 33048576);
  float* wE     = (float*)(ws + 33048576);  // alias, dead before aggregate
  unsigned short* WTt1 = (unsigned short*)(ws + 58648576);
  unsigned short* WTt0 = (unsigned short*)(ws + 58779648);
  unsigned short* WTc1 = (unsigned short*)(ws + 58910720);
  unsigned short* WTc0 = (unsigned short*)(ws + 59172864);

  hipMemsetAsync(ws, 0, 1048576, stream);  // deg, cnt, cursor, stats

  transpose_w<<<dim3(8, 8), 256, 0, stream>>>(Wt1, WTt1, 256, 256);
  transpose_w<<<dim3(8, 8), 256, 0, stream>>>(Wt0, WTt0, 256, 256);
  transpose_w<<<dim3(16, 8), 256, 0, stream>>>(Wc1, WTc1, 512, 256);
  transpose_w<<<dim3(16, 8), 256, 0, stream>>>(Wc0, WTc0, 512, 256);

  edge_mlp_kernel<<<3125, 256, 0, stream>>>(ea, Wm1, bm1, Wm2, bm2, ei, wE, deg, cnt);
  scan1_kernel<<<196, 256, 0, stream>>>(cnt, blockSum);
  scan2_kernel<<<1, 256, 0, stream>>>(blockSum);
  scan3_kernel<<<196, 256, 0, stream>>>(cnt, blockSum, startA, cursor);
  gemm_transform<<<dim3(2, 391), 256, 0, stream>>>(x, WTt1, WTt0, bt1, bt0, msk, xmb);
  wnorm_fill_kernel<<<3125, 256, 0, stream>>>(ei, deg, wE, cursor, colS, wS);
  aggregate_kernel<<<12500, 256, 0, stream>>>(startA, cnt, colS, wS, xmb, aggb);
  stats_kernel<<<250, 256, 0, stream>>>(aggb, S1, S2);
  finalize_kernel<<<1, 256, 0, stream>>>(S1, S2, gnw, gnb, gna, scaleP, shiftP);
  gemm_combine<<<dim3(2, 391), 256, 0, stream>>>(aggb, scaleP, shiftP, x, WTc1, WTc0,
                                                 bc1, bc0, msk, (float*)d_out);
}